// Round 1
// baseline (579.525 us; speedup 1.0000x reference)
//
#include <hip/hip_runtime.h>

#define NB_ 32
#define NP_ 65536
#define NT_ 16

__device__ __forceinline__ unsigned long long shfl_down_u64(unsigned long long v, int off) {
    unsigned lo = (unsigned)(v & 0xffffffffULL);
    unsigned hi = (unsigned)(v >> 32);
    lo = __shfl_down(lo, off, 64);
    hi = __shfl_down(hi, off, 64);
    return (((unsigned long long)hi) << 32) | (unsigned long long)lo;
}

// Phase A: per-prior best-truth (max/argmax over 16 truths) + per-truth best-prior
// (argmax over priors, first-max-wins via packed (iou_bits, ~p) u64 atomicMax).
__global__ void phaseA(const float* __restrict__ priors, const float* __restrict__ targets,
                       float* __restrict__ btl, unsigned char* __restrict__ bti,
                       unsigned long long* __restrict__ bestPrior) {
    int b = blockIdx.y;
    __shared__ float tr[NT_][4];
    __shared__ float ta[NT_];
    int tid = threadIdx.x;  // 256
    if (tid < NT_) {
        const float* tp = targets + ((size_t)b * NT_ + tid) * 5;
        float x0 = tp[0], y0 = tp[1], x1 = tp[2], y1 = tp[3];
        tr[tid][0] = x0; tr[tid][1] = y0; tr[tid][2] = x1; tr[tid][3] = y1;
        ta[tid] = (x1 - x0) * (y1 - y0);
    }
    __syncthreads();

    unsigned long long best[NT_];
#pragma unroll
    for (int t = 0; t < NT_; t++) best[t] = 0ULL;

    int base = blockIdx.x * 1024;
    for (int i = 0; i < 4; i++) {
        int p = base + i * 256 + tid;
        float4 pr = ((const float4*)priors)[p];
        float hw = pr.z * 0.5f, hh = pr.w * 0.5f;
        float bx0 = pr.x - hw, by0 = pr.y - hh;
        float bx1 = pr.x + hw, by1 = pr.y + hh;
        float areab = (bx1 - bx0) * (by1 - by0);
        float bestI = -1.0f;
        int bestT = 0;
#pragma unroll
        for (int t = 0; t < NT_; t++) {
            float lx = fmaxf(tr[t][0], bx0), ly = fmaxf(tr[t][1], by0);
            float rx = fminf(tr[t][2], bx1), ry = fminf(tr[t][3], by1);
            float w = fmaxf(rx - lx, 0.0f), h = fmaxf(ry - ly, 0.0f);
            float inter = w * h;
            float iou = inter / (ta[t] + areab - inter);
            if (iou > bestI) { bestI = iou; bestT = t; }  // first-max-wins (t ascending)
            unsigned long long pk =
                (((unsigned long long)__float_as_uint(iou)) << 32) | (unsigned)(~p);
            if (pk > best[t]) best[t] = pk;
        }
        size_t bp = (size_t)b * NP_ + p;
        btl[bp] = bestI;
        bti[bp] = (unsigned char)bestT;
    }

    // wave-level reduce then one global atomicMax per truth per wave
#pragma unroll
    for (int t = 0; t < NT_; t++) {
        unsigned long long v = best[t];
        for (int off = 32; off > 0; off >>= 1) {
            unsigned long long u = shfl_down_u64(v, off);
            if (u > v) v = u;
        }
        if ((tid & 63) == 0)
            atomicMax(&bestPrior[b * NT_ + t], v);
    }
}

// Phase B: sequential per-batch override (last-wins matches scatter row order).
__global__ void phaseB(const unsigned long long* __restrict__ bestPrior,
                       float* __restrict__ btl, unsigned char* __restrict__ bti) {
    int b = threadIdx.x;
    if (b >= NB_) return;
    for (int t = 0; t < NT_; t++) {
        unsigned long long pk = bestPrior[b * NT_ + t];
        unsigned p = ~((unsigned)(pk & 0xffffffffULL));
        size_t bp = (size_t)b * NP_ + p;
        btl[bp] = 2.0f;
        bti[bp] = (unsigned char)t;
    }
}

// Phase C: per-prior losses; block reduce; store loss_c_mine for mining.
__global__ void phaseC(const float* __restrict__ loc, const float* __restrict__ conf,
                       const float* __restrict__ priors, const float* __restrict__ targets,
                       const float* __restrict__ btl, const unsigned char* __restrict__ bti,
                       float* __restrict__ mine, int* __restrict__ num_pos,
                       float* __restrict__ sums) {
    int b = blockIdx.y;
    __shared__ float tr[NT_][4];
    int tid = threadIdx.x;  // 256
    if (tid < NT_) {
        const float* tp = targets + ((size_t)b * NT_ + tid) * 5;
        tr[tid][0] = tp[0]; tr[tid][1] = tp[1]; tr[tid][2] = tp[2]; tr[tid][3] = tp[3];
    }
    __syncthreads();

    int p = blockIdx.x * 256 + tid;
    size_t bp = (size_t)b * NP_ + p;
    float overlap = btl[bp];
    bool pos = !(overlap < 0.5f);

    float2 c = ((const float2*)conf)[bp];
    float m = fmaxf(c.x, c.y);
    float lse = m + logf(expf(c.x - m) + expf(c.y - m));
    float lca = lse - (pos ? c.y : c.x);
    mine[bp] = pos ? 0.0f : lca;

    float ll = 0.0f;
    float pc = 0.0f;
    int np = 0;
    if (pos) {
        np = 1;
        pc = lca;
        int t = bti[bp];
        float4 pr = ((const float4*)priors)[p];
        float tx0 = tr[t][0], ty0 = tr[t][1], tx1 = tr[t][2], ty1 = tr[t][3];
        float gcx = ((tx0 + tx1) * 0.5f - pr.x) / (0.1f * pr.z);
        float gcy = ((ty0 + ty1) * 0.5f - pr.y) / (0.1f * pr.w);
        float gw = logf((tx1 - tx0) / pr.z) / 0.2f;
        float gh = logf((ty1 - ty0) / pr.w) / 0.2f;
        float4 ld = ((const float4*)loc)[bp];
        float d0 = fabsf(ld.x - gcx), d1 = fabsf(ld.y - gcy);
        float d2 = fabsf(ld.z - gw),  d3 = fabsf(ld.w - gh);
        ll  = (d0 < 1.0f) ? 0.5f * d0 * d0 : d0 - 0.5f;
        ll += (d1 < 1.0f) ? 0.5f * d1 * d1 : d1 - 0.5f;
        ll += (d2 < 1.0f) ? 0.5f * d2 * d2 : d2 - 0.5f;
        ll += (d3 < 1.0f) ? 0.5f * d3 * d3 : d3 - 0.5f;
    }

    // block reduction: 4 waves
    __shared__ float red_ll[4], red_pc[4];
    __shared__ int red_np[4];
    int wave = tid >> 6, lane = tid & 63;
    for (int off = 32; off > 0; off >>= 1) {
        ll += __shfl_down(ll, off, 64);
        pc += __shfl_down(pc, off, 64);
        np += __shfl_down(np, off, 64);
    }
    if (lane == 0) { red_ll[wave] = ll; red_pc[wave] = pc; red_np[wave] = np; }
    __syncthreads();
    if (tid == 0) {
        float a = 0.0f, cc = 0.0f; int n = 0;
        for (int w = 0; w < 4; w++) { a += red_ll[w]; cc += red_pc[w]; n += red_np[w]; }
        if (a != 0.0f) atomicAdd(&sums[0], a);
        if (cc != 0.0f) atomicAdd(&sums[1], cc);
        if (n) atomicAdd(&num_pos[b], n);
    }
}

// Phase D: per-batch exact top-K sum via 3-level bit-histogram selection.
// Level bins: bits[31:20] (4096), bits[19:8] (4096), bits[7:0] (256).
__global__ void __launch_bounds__(1024) phaseD(const float* __restrict__ mine,
                                               const int* __restrict__ num_pos,
                                               float* __restrict__ sums) {
    int b = blockIdx.x;
    const float* v = mine + (size_t)b * NP_;
    int K = 3 * num_pos[b];
    if (K > NP_ - 1) K = NP_ - 1;
    if (K <= 0) return;

    __shared__ unsigned cnt[4096];
    __shared__ float sm[4096];
    __shared__ unsigned ccnt[64];
    __shared__ float csm[64];
    __shared__ unsigned sh_need, sh_prefix;
    __shared__ float sh_acc;

    int tid = threadIdx.x;  // 1024
    if (tid == 0) { sh_need = (unsigned)K; sh_prefix = 0u; sh_acc = 0.0f; }
    __syncthreads();

    for (int level = 0; level < 3; level++) {
        int NBINS = (level == 2) ? 256 : 4096;
        for (int i = tid; i < NBINS; i += 1024) { cnt[i] = 0u; sm[i] = 0.0f; }
        __syncthreads();
        unsigned pfx = sh_prefix;
        for (int i = tid; i < NP_; i += 1024) {
            float x = v[i];
            unsigned bits = __float_as_uint(x);
            bool ok; unsigned bin;
            if (level == 0)      { ok = true;                  bin = bits >> 20; }
            else if (level == 1) { ok = ((bits >> 20) == pfx); bin = (bits >> 8) & 0xFFFu; }
            else                 { ok = ((bits >> 8) == pfx);  bin = bits & 0xFFu; }
            if (ok) { atomicAdd(&cnt[bin], 1u); atomicAdd(&sm[bin], x); }
        }
        __syncthreads();
        int CW = (level == 2) ? 16 : 64;
        int NC = NBINS / CW;
        if (tid < NC) {
            unsigned c = 0; float s = 0.0f;
            for (int j = 0; j < CW; j++) { c += cnt[tid * CW + j]; s += sm[tid * CW + j]; }
            ccnt[tid] = c; csm[tid] = s;
        }
        __syncthreads();
        if (tid == 0) {
            unsigned need = sh_need;
            unsigned cum = 0; float s = 0.0f;
            int cb = NC - 1;
            for (; cb > 0; --cb) {
                if (cum + ccnt[cb] >= need) break;
                cum += ccnt[cb]; s += csm[cb];
            }
            int bin = cb * CW + CW - 1;
            for (; bin > cb * CW; --bin) {
                if (cum + cnt[bin] >= need) break;
                cum += cnt[bin]; s += sm[bin];
            }
            sh_acc += s;
            sh_need = need - cum;  // in [1, cnt[bin]]
            if (level == 0) sh_prefix = (unsigned)bin;
            else if (level == 1) sh_prefix = (sh_prefix << 12) | (unsigned)bin;
            else {
                float vk = __uint_as_float((sh_prefix << 8) | (unsigned)bin);
                sh_acc += (float)sh_need * vk;
            }
        }
        __syncthreads();
    }
    if (tid == 0) atomicAdd(&sums[2], sh_acc);
}

__global__ void finalize(const int* __restrict__ num_pos, const float* __restrict__ sums,
                         float* __restrict__ out) {
    int N = 0;
    for (int b = 0; b < NB_; b++) N += num_pos[b];
    float fn = (float)N;
    out[0] = sums[0] / fn;
    out[1] = (sums[1] + sums[2]) / fn;
}

extern "C" void kernel_launch(void* const* d_in, const int* in_sizes, int n_in,
                              void* d_out, int out_size, void* d_ws, size_t ws_size,
                              hipStream_t stream) {
    const float* loc = (const float*)d_in[0];      // 32*65536*4
    const float* conf = (const float*)d_in[1];     // 32*65536*2
    const float* priors = (const float*)d_in[2];   // 65536*4
    const float* targets = (const float*)d_in[3];  // 32*16*5
    float* out = (float*)d_out;

    char* w = (char*)d_ws;
    float* btl = (float*)w;                                   // 8 MB
    unsigned char* bti = (unsigned char*)(w + (8u << 20));    // 2 MB
    float* mine = (float*)(w + (10u << 20));                  // 8 MB
    char* acc = w + (18u << 20);
    unsigned long long* bestPrior = (unsigned long long*)acc; // 32*16*8 = 4 KB
    int* num_pos = (int*)(acc + 4096);                        // 128 B
    float* sums = (float*)(acc + 4096 + 128);                 // 3 floats

    hipMemsetAsync(acc, 0, 8192, stream);
    phaseA<<<dim3(64, 32), 256, 0, stream>>>(priors, targets, btl, bti, bestPrior);
    phaseB<<<1, 32, 0, stream>>>(bestPrior, btl, bti);
    phaseC<<<dim3(256, 32), 256, 0, stream>>>(loc, conf, priors, targets, btl, bti,
                                              mine, num_pos, sums);
    phaseD<<<32, 1024, 0, stream>>>(mine, num_pos, sums);
    finalize<<<1, 1, 0, stream>>>(num_pos, sums, out);
}

// Round 2
// 262.609 us; speedup vs baseline: 2.2068x; 2.2068x over previous
//
#include <hip/hip_runtime.h>

#define NB_ 32
#define NP_ 65536
#define NT_ 16

__device__ __forceinline__ unsigned long long shfl_down_u64(unsigned long long v, int off) {
    unsigned lo = (unsigned)(v & 0xffffffffULL);
    unsigned hi = (unsigned)(v >> 32);
    lo = __shfl_down(lo, off, 64);
    hi = __shfl_down(hi, off, 64);
    return (((unsigned long long)hi) << 32) | (unsigned long long)lo;
}

// Fused phase A+C: per-prior best-truth, pos mask, conf/loc losses, mine[],
// per-truth best-prior. All accumulators per-batch; block partials reduced
// in-register/LDS first (no same-address atomic storms).
__global__ void __launch_bounds__(256) fusedAC(
    const float* __restrict__ loc, const float* __restrict__ conf,
    const float* __restrict__ priors, const float* __restrict__ targets,
    float* __restrict__ mine, unsigned long long* __restrict__ bestPrior,
    int* __restrict__ num_pos, float* __restrict__ sums_ll, float* __restrict__ sums_pc)
{
    int b = blockIdx.y;
    __shared__ float tr[NT_][4];
    __shared__ float ta[NT_];
    __shared__ unsigned long long shb[4][NT_];
    __shared__ float sh_ll[4], sh_pc[4];
    __shared__ int sh_np[4];

    int tid = threadIdx.x;  // 256
    if (tid < NT_) {
        const float* tp = targets + ((size_t)b * NT_ + tid) * 5;
        float x0 = tp[0], y0 = tp[1], x1 = tp[2], y1 = tp[3];
        tr[tid][0] = x0; tr[tid][1] = y0; tr[tid][2] = x1; tr[tid][3] = y1;
        ta[tid] = (x1 - x0) * (y1 - y0);
    }
    __syncthreads();

    unsigned long long best[NT_];
#pragma unroll
    for (int t = 0; t < NT_; t++) best[t] = 0ULL;
    float ll_acc = 0.0f, pc_acc = 0.0f;
    int np_acc = 0;

    int base = blockIdx.x * 2048;
    for (int it = 0; it < 8; it++) {
        int p = base + it * 256 + tid;
        float4 pr = ((const float4*)priors)[p];
        float hw = pr.z * 0.5f, hh = pr.w * 0.5f;
        float bx0 = pr.x - hw, by0 = pr.y - hh;
        float bx1 = pr.x + hw, by1 = pr.y + hh;
        float areab = (bx1 - bx0) * (by1 - by0);
        float bestI = -1.0f;
        int bestT = 0;
#pragma unroll
        for (int t = 0; t < NT_; t++) {
            float lx = fmaxf(tr[t][0], bx0), ly = fmaxf(tr[t][1], by0);
            float rx = fminf(tr[t][2], bx1), ry = fminf(tr[t][3], by1);
            float w = fmaxf(rx - lx, 0.0f), h = fmaxf(ry - ly, 0.0f);
            float inter = w * h;
            float iou = inter / (ta[t] + areab - inter);
            if (iou > bestI) { bestI = iou; bestT = t; }  // first-max-wins (t asc)
            unsigned long long pk =
                (((unsigned long long)__float_as_uint(iou)) << 32) | (unsigned)(~p);
            if (pk > best[t]) best[t] = pk;
        }
        size_t bp = (size_t)b * NP_ + p;
        bool pos = !(bestI < 0.5f);
        float2 c = ((const float2*)conf)[bp];
        float m = fmaxf(c.x, c.y);
        float lse = m + __logf(__expf(c.x - m) + __expf(c.y - m));
        mine[bp] = pos ? 0.0f : (lse - c.x);
        if (pos) {
            np_acc++;
            pc_acc += lse - c.y;
            int t = bestT;
            float tx0 = tr[t][0], ty0 = tr[t][1], tx1 = tr[t][2], ty1 = tr[t][3];
            float gcx = ((tx0 + tx1) * 0.5f - pr.x) / (0.1f * pr.z);
            float gcy = ((ty0 + ty1) * 0.5f - pr.y) / (0.1f * pr.w);
            float gw = __logf((tx1 - tx0) / pr.z) * 5.0f;
            float gh = __logf((ty1 - ty0) / pr.w) * 5.0f;
            float4 ld = ((const float4*)loc)[bp];
            float d0 = fabsf(ld.x - gcx), d1 = fabsf(ld.y - gcy);
            float d2 = fabsf(ld.z - gw),  d3 = fabsf(ld.w - gh);
            ll_acc += (d0 < 1.0f) ? 0.5f * d0 * d0 : d0 - 0.5f;
            ll_acc += (d1 < 1.0f) ? 0.5f * d1 * d1 : d1 - 0.5f;
            ll_acc += (d2 < 1.0f) ? 0.5f * d2 * d2 : d2 - 0.5f;
            ll_acc += (d3 < 1.0f) ? 0.5f * d3 * d3 : d3 - 0.5f;
        }
    }

    int wave = tid >> 6, lane = tid & 63;
#pragma unroll
    for (int t = 0; t < NT_; t++) {
        unsigned long long v = best[t];
        for (int off = 32; off > 0; off >>= 1) {
            unsigned long long u = shfl_down_u64(v, off);
            if (u > v) v = u;
        }
        if (lane == 0) shb[wave][t] = v;
    }
    for (int off = 32; off > 0; off >>= 1) {
        ll_acc += __shfl_down(ll_acc, off, 64);
        pc_acc += __shfl_down(pc_acc, off, 64);
        np_acc += __shfl_down(np_acc, off, 64);
    }
    if (lane == 0) { sh_ll[wave] = ll_acc; sh_pc[wave] = pc_acc; sh_np[wave] = np_acc; }
    __syncthreads();
    if (tid < NT_) {
        unsigned long long v = shb[0][tid];
        for (int w = 1; w < 4; w++) { unsigned long long u = shb[w][tid]; if (u > v) v = u; }
        atomicMax(&bestPrior[b * NT_ + tid], v);   // 32 blocks per address
    }
    if (tid == 0) {
        float a = sh_ll[0] + sh_ll[1] + sh_ll[2] + sh_ll[3];
        float c2 = sh_pc[0] + sh_pc[1] + sh_pc[2] + sh_pc[3];
        int n = sh_np[0] + sh_np[1] + sh_np[2] + sh_np[3];
        if (a != 0.0f) atomicAdd(&sums_ll[b], a);    // per-batch: 32 writers max
        if (c2 != 0.0f) atomicAdd(&sums_pc[b], c2);
        if (n) atomicAdd(&num_pos[b], n);
    }
}

// Force-match correction: for each (b,t) best prior p*, replace its original
// contribution with the forced-pos contribution (last-wins dedup like scatter).
__global__ void fixup(const float* __restrict__ loc, const float* __restrict__ conf,
                      const float* __restrict__ priors, const float* __restrict__ targets,
                      const unsigned long long* __restrict__ bestPrior,
                      float* __restrict__ mine, int* __restrict__ num_pos,
                      float* __restrict__ sums_ll, float* __restrict__ sums_pc)
{
    int b = blockIdx.x;
    int t = threadIdx.x;  // 64 threads, 16 active
    __shared__ unsigned ps[NT_];
    __shared__ float tr[NT_][4];
    __shared__ float ta[NT_];
    if (t < NT_) {
        ps[t] = ~((unsigned)(bestPrior[b * NT_ + t] & 0xffffffffULL));
        const float* tp = targets + ((size_t)b * NT_ + t) * 5;
        tr[t][0] = tp[0]; tr[t][1] = tp[1]; tr[t][2] = tp[2]; tr[t][3] = tp[3];
        ta[t] = (tp[2] - tp[0]) * (tp[3] - tp[1]);
    }
    __syncthreads();
    if (t >= NT_) return;
    unsigned p = ps[t];
    for (int u = t + 1; u < NT_; u++)
        if (ps[u] == p) return;  // a later truth overwrites this prior: skip (last-wins)

    float4 pr = ((const float4*)priors)[p];
    float hw = pr.z * 0.5f, hh = pr.w * 0.5f;
    float bx0 = pr.x - hw, by0 = pr.y - hh;
    float bx1 = pr.x + hw, by1 = pr.y + hh;
    float areab = (bx1 - bx0) * (by1 - by0);
    float bestI = -1.0f;
    int t0 = 0;
#pragma unroll
    for (int tt = 0; tt < NT_; tt++) {
        float lx = fmaxf(tr[tt][0], bx0), ly = fmaxf(tr[tt][1], by0);
        float rx = fminf(tr[tt][2], bx1), ry = fminf(tr[tt][3], by1);
        float w = fmaxf(rx - lx, 0.0f), h = fmaxf(ry - ly, 0.0f);
        float inter = w * h;
        float iou = inter / (ta[tt] + areab - inter);
        if (iou > bestI) { bestI = iou; t0 = tt; }
    }
    bool pos0 = !(bestI < 0.5f);

    size_t bp = (size_t)b * NP_ + p;
    float2 c = ((const float2*)conf)[bp];
    float m = fmaxf(c.x, c.y);
    float lse = m + __logf(__expf(c.x - m) + __expf(c.y - m));
    float4 ld = ((const float4*)loc)[bp];

    auto sl1_of = [&](int tt) -> float {
        float tx0 = tr[tt][0], ty0 = tr[tt][1], tx1 = tr[tt][2], ty1 = tr[tt][3];
        float gcx = ((tx0 + tx1) * 0.5f - pr.x) / (0.1f * pr.z);
        float gcy = ((ty0 + ty1) * 0.5f - pr.y) / (0.1f * pr.w);
        float gw = __logf((tx1 - tx0) / pr.z) * 5.0f;
        float gh = __logf((ty1 - ty0) / pr.w) * 5.0f;
        float d0 = fabsf(ld.x - gcx), d1 = fabsf(ld.y - gcy);
        float d2 = fabsf(ld.z - gw),  d3 = fabsf(ld.w - gh);
        float s = (d0 < 1.0f) ? 0.5f * d0 * d0 : d0 - 0.5f;
        s += (d1 < 1.0f) ? 0.5f * d1 * d1 : d1 - 0.5f;
        s += (d2 < 1.0f) ? 0.5f * d2 * d2 : d2 - 0.5f;
        s += (d3 < 1.0f) ? 0.5f * d3 * d3 : d3 - 0.5f;
        return s;
    };

    float dll = sl1_of(t) - (pos0 ? sl1_of(t0) : 0.0f);
    float dpc = pos0 ? 0.0f : (lse - c.y);
    mine[bp] = 0.0f;  // forced pos -> excluded from mining
    if (dll != 0.0f) atomicAdd(&sums_ll[b], dll);
    if (dpc != 0.0f) atomicAdd(&sums_pc[b], dpc);
    if (!pos0) atomicAdd(&num_pos[b], 1);
}

// Phase D: per-batch exact top-K sum via 3-level bit-histogram selection.
__global__ void __launch_bounds__(1024) phaseD(const float* __restrict__ mine,
                                               const int* __restrict__ num_pos,
                                               float* __restrict__ topk) {
    int b = blockIdx.x;
    const float* v = mine + (size_t)b * NP_;
    int K = 3 * num_pos[b];
    if (K > NP_ - 1) K = NP_ - 1;

    __shared__ unsigned cnt[4096];
    __shared__ float sm[4096];
    __shared__ unsigned ccnt[64];
    __shared__ float csm[64];
    __shared__ unsigned sh_need, sh_prefix;
    __shared__ float sh_acc;

    int tid = threadIdx.x;  // 1024
    if (K <= 0) { if (tid == 0) topk[b] = 0.0f; return; }
    if (tid == 0) { sh_need = (unsigned)K; sh_prefix = 0u; sh_acc = 0.0f; }
    __syncthreads();

    for (int level = 0; level < 3; level++) {
        int NBINS = (level == 2) ? 256 : 4096;
        for (int i = tid; i < NBINS; i += 1024) { cnt[i] = 0u; sm[i] = 0.0f; }
        __syncthreads();
        unsigned pfx = sh_prefix;
        for (int i = tid; i < NP_; i += 1024) {
            float x = v[i];
            unsigned bits = __float_as_uint(x);
            bool ok; unsigned bin;
            if (level == 0)      { ok = true;                  bin = bits >> 20; }
            else if (level == 1) { ok = ((bits >> 20) == pfx); bin = (bits >> 8) & 0xFFFu; }
            else                 { ok = ((bits >> 8) == pfx);  bin = bits & 0xFFu; }
            if (ok) { atomicAdd(&cnt[bin], 1u); atomicAdd(&sm[bin], x); }
        }
        __syncthreads();
        int CW = (level == 2) ? 16 : 64;
        int NC = NBINS / CW;
        if (tid < NC) {
            unsigned c = 0; float s = 0.0f;
            for (int j = 0; j < CW; j++) { c += cnt[tid * CW + j]; s += sm[tid * CW + j]; }
            ccnt[tid] = c; csm[tid] = s;
        }
        __syncthreads();
        if (tid == 0) {
            unsigned need = sh_need;
            unsigned cum = 0; float s = 0.0f;
            int cb = NC - 1;
            for (; cb > 0; --cb) {
                if (cum + ccnt[cb] >= need) break;
                cum += ccnt[cb]; s += csm[cb];
            }
            int bin = cb * CW + CW - 1;
            for (; bin > cb * CW; --bin) {
                if (cum + cnt[bin] >= need) break;
                cum += cnt[bin]; s += sm[bin];
            }
            sh_acc += s;
            sh_need = need - cum;  // in [1, cnt[bin]]
            if (level == 0) sh_prefix = (unsigned)bin;
            else if (level == 1) sh_prefix = (sh_prefix << 12) | (unsigned)bin;
            else {
                float vk = __uint_as_float((sh_prefix << 8) | (unsigned)bin);
                sh_acc += (float)sh_need * vk;
            }
        }
        __syncthreads();
    }
    if (tid == 0) topk[b] = sh_acc;  // plain store, no atomic
}

__global__ void finalize(const int* __restrict__ num_pos, const float* __restrict__ sums_ll,
                         const float* __restrict__ sums_pc, const float* __restrict__ topk,
                         float* __restrict__ out) {
    int t = threadIdx.x;  // 64
    float ll = 0.0f, pc = 0.0f, tk = 0.0f;
    int n = 0;
    if (t < NB_) { ll = sums_ll[t]; pc = sums_pc[t]; tk = topk[t]; n = num_pos[t]; }
    for (int off = 32; off > 0; off >>= 1) {
        ll += __shfl_down(ll, off, 64);
        pc += __shfl_down(pc, off, 64);
        tk += __shfl_down(tk, off, 64);
        n  += __shfl_down(n, off, 64);
    }
    if (t == 0) {
        float fn = (float)n;
        out[0] = ll / fn;
        out[1] = (pc + tk) / fn;
    }
}

extern "C" void kernel_launch(void* const* d_in, const int* in_sizes, int n_in,
                              void* d_out, int out_size, void* d_ws, size_t ws_size,
                              hipStream_t stream) {
    const float* loc = (const float*)d_in[0];      // 32*65536*4
    const float* conf = (const float*)d_in[1];     // 32*65536*2
    const float* priors = (const float*)d_in[2];   // 65536*4
    const float* targets = (const float*)d_in[3];  // 32*16*5
    float* out = (float*)d_out;

    char* w = (char*)d_ws;
    float* mine = (float*)w;                                        // 8 MB
    char* acc = w + (8u << 20);
    unsigned long long* bestPrior = (unsigned long long*)acc;       // 512*8 = 4096 B
    int* num_pos = (int*)(acc + 4096);                              // 128 B
    float* sums_ll = (float*)(acc + 4096 + 128);                    // 128 B
    float* sums_pc = (float*)(acc + 4096 + 256);                    // 128 B
    float* topk    = (float*)(acc + 4096 + 384);                    // 128 B

    hipMemsetAsync(acc, 0, 8192, stream);
    fusedAC<<<dim3(32, 32), 256, 0, stream>>>(loc, conf, priors, targets, mine,
                                              bestPrior, num_pos, sums_ll, sums_pc);
    fixup<<<NB_, 64, 0, stream>>>(loc, conf, priors, targets, bestPrior, mine,
                                  num_pos, sums_ll, sums_pc);
    phaseD<<<NB_, 1024, 0, stream>>>(mine, num_pos, topk);
    finalize<<<1, 64, 0, stream>>>(num_pos, sums_ll, sums_pc, topk, out);
}

// Round 3
// 209.392 us; speedup vs baseline: 2.7677x; 1.2541x over previous
//
#include <hip/hip_runtime.h>

#define NB_ 32
#define NP_ 65536
#define NT_ 16
#define D1B 8
#define BINS 4096
#define FBINS 256
#define SCALE 512.0f

__device__ __forceinline__ unsigned long long shfl_down_u64(unsigned long long v, int off) {
    unsigned lo = (unsigned)(v & 0xffffffffULL);
    unsigned hi = (unsigned)(v >> 32);
    lo = __shfl_down(lo, off, 64);
    hi = __shfl_down(hi, off, 64);
    return (((unsigned long long)hi) << 32) | (unsigned long long)lo;
}

// Fused A+C, 4-prior chunks: tr[t] LDS reads amortized over 4 priors,
// u64 pack/compare once per truth per chunk.
__global__ void __launch_bounds__(256) fusedAC(
    const float* __restrict__ loc, const float* __restrict__ conf,
    const float* __restrict__ priors, const float* __restrict__ targets,
    float* __restrict__ mine, unsigned long long* __restrict__ bestPrior,
    int* __restrict__ num_pos, float* __restrict__ sums_ll, float* __restrict__ sums_pc)
{
    int b = blockIdx.y;
    __shared__ float tr[NT_][5];  // x0,y0,x1,y1,area
    __shared__ unsigned long long shb[4][NT_];
    __shared__ float sh_ll[4], sh_pc[4];
    __shared__ int sh_np[4];

    int tid = threadIdx.x;  // 256
    if (tid < NT_) {
        const float* tp = targets + ((size_t)b * NT_ + tid) * 5;
        float x0 = tp[0], y0 = tp[1], x1 = tp[2], y1 = tp[3];
        tr[tid][0] = x0; tr[tid][1] = y0; tr[tid][2] = x1; tr[tid][3] = y1;
        tr[tid][4] = (x1 - x0) * (y1 - y0);
    }
    __syncthreads();

    int p0 = blockIdx.x * 1024 + tid;  // chunk priors: p0 + 256*i, i=0..3
    float bx0[4], by0[4], bx1[4], by1[4], ar[4];
#pragma unroll
    for (int i = 0; i < 4; i++) {
        float4 pr = ((const float4*)priors)[p0 + 256 * i];
        float hw = pr.z * 0.5f, hh = pr.w * 0.5f;
        bx0[i] = pr.x - hw; by0[i] = pr.y - hh;
        bx1[i] = pr.x + hw; by1[i] = pr.y + hh;
        ar[i] = (bx1[i] - bx0[i]) * (by1[i] - by0[i]);
    }
    float bestI[4] = {-1.f, -1.f, -1.f, -1.f};
    int bestT[4] = {0, 0, 0, 0};
    unsigned long long best[NT_];
#pragma unroll
    for (int t = 0; t < NT_; t++) best[t] = 0ULL;

#pragma unroll
    for (int t = 0; t < NT_; t++) {
        float tx0 = tr[t][0], ty0 = tr[t][1], tx1 = tr[t][2], ty1 = tr[t][3], ta = tr[t][4];
        float mi = -1.0f; int pi = 0;
#pragma unroll
        for (int i = 0; i < 4; i++) {
            float lx = fmaxf(tx0, bx0[i]), ly = fmaxf(ty0, by0[i]);
            float rx = fminf(tx1, bx1[i]), ry = fminf(ty1, by1[i]);
            float w = fmaxf(rx - lx, 0.0f), h = fmaxf(ry - ly, 0.0f);
            float inter = w * h;
            float iou = inter / (ta + ar[i] - inter);
            if (iou > bestI[i]) { bestI[i] = iou; bestT[i] = t; }  // first-wins (t asc)
            if (iou > mi) { mi = iou; pi = i; }                    // first-wins (p asc)
        }
        unsigned long long pk = (((unsigned long long)__float_as_uint(mi)) << 32)
                              | (unsigned)(~(p0 + 256 * pi));
        if (pk > best[t]) best[t] = pk;
    }

    float ll_acc = 0.0f, pc_acc = 0.0f;
    int np_acc = 0;
#pragma unroll
    for (int i = 0; i < 4; i++) {
        int p = p0 + 256 * i;
        size_t bp = (size_t)b * NP_ + p;
        bool pos = !(bestI[i] < 0.5f);
        float2 c = ((const float2*)conf)[bp];
        float m = fmaxf(c.x, c.y);
        float lse = m + __logf(__expf(c.x - m) + __expf(c.y - m));
        mine[bp] = pos ? 0.0f : (lse - c.x);
        if (pos) {
            np_acc++;
            pc_acc += lse - c.y;
            int t = bestT[i];
            float tx0 = tr[t][0], ty0 = tr[t][1], tx1 = tr[t][2], ty1 = tr[t][3];
            float icx = 1.0f / (0.1f * ((const float4*)priors)[p].z);
            float4 pr = ((const float4*)priors)[p];
            float gcx = ((tx0 + tx1) * 0.5f - pr.x) / (0.1f * pr.z);
            float gcy = ((ty0 + ty1) * 0.5f - pr.y) / (0.1f * pr.w);
            float gw = __logf((tx1 - tx0) / pr.z) * 5.0f;
            float gh = __logf((ty1 - ty0) / pr.w) * 5.0f;
            float4 ld = ((const float4*)loc)[bp];
            float d0 = fabsf(ld.x - gcx), d1 = fabsf(ld.y - gcy);
            float d2 = fabsf(ld.z - gw),  d3 = fabsf(ld.w - gh);
            ll_acc += (d0 < 1.0f) ? 0.5f * d0 * d0 : d0 - 0.5f;
            ll_acc += (d1 < 1.0f) ? 0.5f * d1 * d1 : d1 - 0.5f;
            ll_acc += (d2 < 1.0f) ? 0.5f * d2 * d2 : d2 - 0.5f;
            ll_acc += (d3 < 1.0f) ? 0.5f * d3 * d3 : d3 - 0.5f;
            (void)icx;
        }
    }

    int wave = tid >> 6, lane = tid & 63;
#pragma unroll
    for (int t = 0; t < NT_; t++) {
        unsigned long long v = best[t];
        for (int off = 32; off > 0; off >>= 1) {
            unsigned long long u = shfl_down_u64(v, off);
            if (u > v) v = u;
        }
        if (lane == 0) shb[wave][t] = v;
    }
    for (int off = 32; off > 0; off >>= 1) {
        ll_acc += __shfl_down(ll_acc, off, 64);
        pc_acc += __shfl_down(pc_acc, off, 64);
        np_acc += __shfl_down(np_acc, off, 64);
    }
    if (lane == 0) { sh_ll[wave] = ll_acc; sh_pc[wave] = pc_acc; sh_np[wave] = np_acc; }
    __syncthreads();
    if (tid < NT_) {
        unsigned long long v = shb[0][tid];
        for (int w = 1; w < 4; w++) { unsigned long long u = shb[w][tid]; if (u > v) v = u; }
        atomicMax(&bestPrior[b * NT_ + tid], v);
    }
    if (tid == 0) {
        float a = sh_ll[0] + sh_ll[1] + sh_ll[2] + sh_ll[3];
        float c2 = sh_pc[0] + sh_pc[1] + sh_pc[2] + sh_pc[3];
        int n = sh_np[0] + sh_np[1] + sh_np[2] + sh_np[3];
        if (a != 0.0f) atomicAdd(&sums_ll[b], a);
        if (c2 != 0.0f) atomicAdd(&sums_pc[b], c2);
        if (n) atomicAdd(&num_pos[b], n);
    }
}

// Force-match correction (unchanged from R2, verified exact).
__global__ void fixup(const float* __restrict__ loc, const float* __restrict__ conf,
                      const float* __restrict__ priors, const float* __restrict__ targets,
                      const unsigned long long* __restrict__ bestPrior,
                      float* __restrict__ mine, int* __restrict__ num_pos,
                      float* __restrict__ sums_ll, float* __restrict__ sums_pc)
{
    int b = blockIdx.x;
    int t = threadIdx.x;  // 64 threads, 16 active
    __shared__ unsigned ps[NT_];
    __shared__ float tr[NT_][4];
    __shared__ float ta[NT_];
    if (t < NT_) {
        ps[t] = ~((unsigned)(bestPrior[b * NT_ + t] & 0xffffffffULL));
        const float* tp = targets + ((size_t)b * NT_ + t) * 5;
        tr[t][0] = tp[0]; tr[t][1] = tp[1]; tr[t][2] = tp[2]; tr[t][3] = tp[3];
        ta[t] = (tp[2] - tp[0]) * (tp[3] - tp[1]);
    }
    __syncthreads();
    if (t >= NT_) return;
    unsigned p = ps[t];
    for (int u = t + 1; u < NT_; u++)
        if (ps[u] == p) return;  // last-wins dedup

    float4 pr = ((const float4*)priors)[p];
    float hw = pr.z * 0.5f, hh = pr.w * 0.5f;
    float bx0 = pr.x - hw, by0 = pr.y - hh;
    float bx1 = pr.x + hw, by1 = pr.y + hh;
    float areab = (bx1 - bx0) * (by1 - by0);
    float bestI = -1.0f;
    int t0 = 0;
#pragma unroll
    for (int tt = 0; tt < NT_; tt++) {
        float lx = fmaxf(tr[tt][0], bx0), ly = fmaxf(tr[tt][1], by0);
        float rx = fminf(tr[tt][2], bx1), ry = fminf(tr[tt][3], by1);
        float w = fmaxf(rx - lx, 0.0f), h = fmaxf(ry - ly, 0.0f);
        float inter = w * h;
        float iou = inter / (ta[tt] + areab - inter);
        if (iou > bestI) { bestI = iou; t0 = tt; }
    }
    bool pos0 = !(bestI < 0.5f);

    size_t bp = (size_t)b * NP_ + p;
    float2 c = ((const float2*)conf)[bp];
    float m = fmaxf(c.x, c.y);
    float lse = m + __logf(__expf(c.x - m) + __expf(c.y - m));
    float4 ld = ((const float4*)loc)[bp];

    auto sl1_of = [&](int tt) -> float {
        float tx0 = tr[tt][0], ty0 = tr[tt][1], tx1 = tr[tt][2], ty1 = tr[tt][3];
        float gcx = ((tx0 + tx1) * 0.5f - pr.x) / (0.1f * pr.z);
        float gcy = ((ty0 + ty1) * 0.5f - pr.y) / (0.1f * pr.w);
        float gw = __logf((tx1 - tx0) / pr.z) * 5.0f;
        float gh = __logf((ty1 - ty0) / pr.w) * 5.0f;
        float d0 = fabsf(ld.x - gcx), d1 = fabsf(ld.y - gcy);
        float d2 = fabsf(ld.z - gw),  d3 = fabsf(ld.w - gh);
        float s = (d0 < 1.0f) ? 0.5f * d0 * d0 : d0 - 0.5f;
        s += (d1 < 1.0f) ? 0.5f * d1 * d1 : d1 - 0.5f;
        s += (d2 < 1.0f) ? 0.5f * d2 * d2 : d2 - 0.5f;
        s += (d3 < 1.0f) ? 0.5f * d3 * d3 : d3 - 0.5f;
        return s;
    };

    float dll = sl1_of(t) - (pos0 ? sl1_of(t0) : 0.0f);
    float dpc = pos0 ? 0.0f : (lse - c.y);
    mine[bp] = 0.0f;
    if (dll != 0.0f) atomicAdd(&sums_ll[b], dll);
    if (dpc != 0.0f) atomicAdd(&sums_pc[b], dpc);
    if (!pos0) atomicAdd(&num_pos[b], 1);
}

// D1: per-(batch, 1/8-slice) linear histogram (counts+sums), plain writeback.
__global__ void __launch_bounds__(256) histD1(const float* __restrict__ mine,
                                              unsigned* __restrict__ hcnt,
                                              float* __restrict__ hsum) {
    int b = blockIdx.y, blk = blockIdx.x;
    __shared__ unsigned cnt[BINS];
    __shared__ float sm[BINS];
    int tid = threadIdx.x;
    for (int i = tid; i < BINS; i += 256) { cnt[i] = 0u; sm[i] = 0.0f; }
    __syncthreads();
    const float4* v4 = (const float4*)(mine + (size_t)b * NP_ + blk * 8192);
    for (int i = tid; i < 2048; i += 256) {
        float4 x = v4[i];
        int b0 = min(BINS - 1, (int)(x.x * SCALE));
        int b1 = min(BINS - 1, (int)(x.y * SCALE));
        int b2 = min(BINS - 1, (int)(x.z * SCALE));
        int b3 = min(BINS - 1, (int)(x.w * SCALE));
        atomicAdd(&cnt[b0], 1u); atomicAdd(&sm[b0], x.x);
        atomicAdd(&cnt[b1], 1u); atomicAdd(&sm[b1], x.y);
        atomicAdd(&cnt[b2], 1u); atomicAdd(&sm[b2], x.z);
        atomicAdd(&cnt[b3], 1u); atomicAdd(&sm[b3], x.w);
    }
    __syncthreads();
    unsigned* gc = hcnt + ((size_t)(b * D1B + blk)) * BINS;
    float* gs = hsum + ((size_t)(b * D1B + blk)) * BINS;
    for (int i = tid; i < BINS; i += 256) { gc[i] = cnt[i]; gs[i] = sm[i]; }
}

// D2: merge 8 sub-hists per batch, find cut bin, sum of full bins above cut.
__global__ void __launch_bounds__(1024) selectD2(const unsigned* __restrict__ hcnt,
                                                 const float* __restrict__ hsum,
                                                 const int* __restrict__ num_pos,
                                                 float* __restrict__ accv,
                                                 int* __restrict__ cutbin,
                                                 unsigned* __restrict__ remv) {
    int b = blockIdx.x;
    __shared__ unsigned cnt[BINS];
    __shared__ float sm[BINS];
    __shared__ unsigned ccnt[64];
    __shared__ float csm[64];
    int tid = threadIdx.x;
    for (int i = tid; i < BINS; i += 1024) {
        unsigned c = 0; float s = 0.0f;
        for (int k = 0; k < D1B; k++) {
            c += hcnt[((size_t)(b * D1B + k)) * BINS + i];
            s += hsum[((size_t)(b * D1B + k)) * BINS + i];
        }
        cnt[i] = c; sm[i] = s;
    }
    __syncthreads();
    if (tid < 64) {
        unsigned c = 0; float s = 0.0f;
        for (int j = 0; j < 64; j++) { c += cnt[tid * 64 + j]; s += sm[tid * 64 + j]; }
        ccnt[tid] = c; csm[tid] = s;
    }
    __syncthreads();
    if (tid == 0) {
        int K = 3 * num_pos[b];
        if (K > NP_ - 1) K = NP_ - 1;
        if (K <= 0) { accv[b] = 0.0f; cutbin[b] = -1; remv[b] = 0u; }
        else {
            unsigned need = (unsigned)K, cum = 0; float s = 0.0f;
            int cb = 63;
            for (; cb > 0; --cb) {
                if (cum + ccnt[cb] >= need) break;
                cum += ccnt[cb]; s += csm[cb];
            }
            int bin = cb * 64 + 63;
            for (; bin > cb * 64; --bin) {
                if (cum + cnt[bin] >= need) break;
                cum += cnt[bin]; s += sm[bin];
            }
            accv[b] = s; cutbin[b] = bin; remv[b] = need - cum;
        }
    }
}

// D3: fine 256-bin sub-histogram of the cut bin's elements (few per batch).
__global__ void __launch_bounds__(256) refineD3(const float* __restrict__ mine,
                                                const int* __restrict__ cutbin,
                                                unsigned* __restrict__ fcnt,
                                                float* __restrict__ fsum) {
    int b = blockIdx.y, blk = blockIdx.x;
    int cb = cutbin[b];
    if (cb < 0) return;
    const float4* v4 = (const float4*)(mine + (size_t)b * NP_ + blk * 8192);
    unsigned* fc = fcnt + b * FBINS;
    float* fs = fsum + b * FBINS;
    int tid = threadIdx.x;
    float fcb = (float)cb;
    for (int i = tid; i < 2048; i += 256) {
        float4 x = v4[i];
        float v[4] = {x.x, x.y, x.z, x.w};
#pragma unroll
        for (int j = 0; j < 4; j++) {
            if (min(BINS - 1, (int)(v[j] * SCALE)) == cb) {
                int fb = min(FBINS - 1, (int)((v[j] * SCALE - fcb) * 256.0f));
                atomicAdd(&fc[fb], 1u);
                atomicAdd(&fs[fb], v[j]);
            }
        }
    }
}

// D4: finish top-K per batch from fine bins; reduce all per-batch scalars.
__global__ void finalD4(const int* __restrict__ num_pos, const float* __restrict__ sums_ll,
                        const float* __restrict__ sums_pc, const float* __restrict__ accv,
                        const int* __restrict__ cutbin, const unsigned* __restrict__ remv,
                        const unsigned* __restrict__ fcnt, const float* __restrict__ fsum,
                        float* __restrict__ out) {
    int t = threadIdx.x;  // 64
    float ll = 0.0f, pc = 0.0f, tk = 0.0f;
    int n = 0;
    if (t < NB_) {
        ll = sums_ll[t]; pc = sums_pc[t]; n = num_pos[t];
        int cb = cutbin[t];
        if (cb >= 0) {
            float s = accv[t];
            unsigned rem = remv[t], cum = 0;
            const unsigned* fc = fcnt + t * FBINS;
            const float* fs = fsum + t * FBINS;
            int fb = FBINS - 1;
            for (; fb > 0; --fb) {
                if (cum + fc[fb] >= rem) break;
                cum += fc[fb]; s += fs[fb];
            }
            float edge = ((float)cb + (float)fb * (1.0f / 256.0f)) * (1.0f / SCALE);
            tk = s + (float)(rem - cum) * edge;
        }
    }
    for (int off = 32; off > 0; off >>= 1) {
        ll += __shfl_down(ll, off, 64);
        pc += __shfl_down(pc, off, 64);
        tk += __shfl_down(tk, off, 64);
        n  += __shfl_down(n, off, 64);
    }
    if (t == 0) {
        float fn = (float)n;
        out[0] = ll / fn;
        out[1] = (pc + tk) / fn;
    }
}

extern "C" void kernel_launch(void* const* d_in, const int* in_sizes, int n_in,
                              void* d_out, int out_size, void* d_ws, size_t ws_size,
                              hipStream_t stream) {
    const float* loc = (const float*)d_in[0];
    const float* conf = (const float*)d_in[1];
    const float* priors = (const float*)d_in[2];
    const float* targets = (const float*)d_in[3];
    float* out = (float*)d_out;

    char* w = (char*)d_ws;
    float* mine = (float*)w;                                   // 8 MB
    unsigned* hcnt = (unsigned*)(w + (8u << 20));              // 4 MB
    float* hsum = (float*)(w + (12u << 20));                   // 4 MB
    char* acc = w + (16u << 20);
    unsigned long long* bestPrior = (unsigned long long*)acc;  // 4096 B
    int* num_pos = (int*)(acc + 4096);                         // 128 B
    float* sums_ll = (float*)(acc + 4224);
    float* sums_pc = (float*)(acc + 4352);
    float* accv    = (float*)(acc + 4480);
    int* cutbin    = (int*)(acc + 4608);
    unsigned* remv = (unsigned*)(acc + 4736);
    unsigned* fcnt = (unsigned*)(acc + 8192);                  // 32 KB
    float* fsum    = (float*)(acc + 8192 + 32768);             // 32 KB

    hipMemsetAsync(acc, 0, 8192 + 65536, stream);
    fusedAC<<<dim3(64, 32), 256, 0, stream>>>(loc, conf, priors, targets, mine,
                                              bestPrior, num_pos, sums_ll, sums_pc);
    fixup<<<NB_, 64, 0, stream>>>(loc, conf, priors, targets, bestPrior, mine,
                                  num_pos, sums_ll, sums_pc);
    histD1<<<dim3(D1B, NB_), 256, 0, stream>>>(mine, hcnt, hsum);
    selectD2<<<NB_, 1024, 0, stream>>>(hcnt, hsum, num_pos, accv, cutbin, remv);
    refineD3<<<dim3(D1B, NB_), 256, 0, stream>>>(mine, cutbin, fcnt, fsum);
    finalD4<<<1, 64, 0, stream>>>(num_pos, sums_ll, sums_pc, accv, cutbin, remv,
                                  fcnt, fsum, out);
}

// Round 4
// 164.849 us; speedup vs baseline: 3.5155x; 1.2702x over previous
//
#include <hip/hip_runtime.h>

#define NB_ 32
#define NP_ 65536
#define NT_ 16
#define HB 1024
#define HSCALE 128.0f

__device__ __forceinline__ unsigned long long shfl_down_u64(unsigned long long v, int off) {
    unsigned lo = (unsigned)(v & 0xffffffffULL);
    unsigned hi = (unsigned)(v >> 32);
    lo = __shfl_down(lo, off, 64);
    hi = __shfl_down(hi, off, 64);
    return (((unsigned long long)hi) << 32) | (unsigned long long)lo;
}

__device__ __forceinline__ float softplus_(float x) {
    // log(1 + e^x), stable
    return fmaxf(x, 0.0f) + __logf(1.0f + __expf(-fabsf(x)));
}

__device__ __forceinline__ float iou_fast(float tx0, float ty0, float tx1, float ty1, float ta,
                                          float bx0, float by0, float bx1, float by1, float ar) {
    float lx = fmaxf(tx0, bx0), ly = fmaxf(ty0, by0);
    float rx = fminf(tx1, bx1), ry = fminf(ty1, by1);
    float w = fmaxf(rx - lx, 0.0f), h = fmaxf(ry - ly, 0.0f);
    float inter = w * h;
    return __fdividef(inter, ta + ar - inter);
}

// Fused A+C+hist: per-prior best-truth, pos losses, per-truth best-prior,
// and the per-batch 1024-bin mining histogram (LDS, zero-skip global merge).
__global__ void __launch_bounds__(256) fusedAC(
    const float* __restrict__ loc, const float* __restrict__ conf,
    const float* __restrict__ priors, const float* __restrict__ targets,
    unsigned long long* __restrict__ bestPrior, int* __restrict__ num_pos,
    float* __restrict__ sums_ll, float* __restrict__ sums_pc,
    int* __restrict__ hcnt, float* __restrict__ hsum)
{
    int b = blockIdx.y;
    __shared__ float tr[NT_][5];  // x0,y0,x1,y1,area
    __shared__ int hc[HB];
    __shared__ float hs[HB];
    __shared__ unsigned long long shb[4][NT_];
    __shared__ float sh_ll[4], sh_pc[4];
    __shared__ int sh_np[4];

    int tid = threadIdx.x;  // 256
    for (int i = tid; i < HB; i += 256) { hc[i] = 0; hs[i] = 0.0f; }
    if (tid < NT_) {
        const float* tp = targets + ((size_t)b * NT_ + tid) * 5;
        float x0 = tp[0], y0 = tp[1], x1 = tp[2], y1 = tp[3];
        tr[tid][0] = x0; tr[tid][1] = y0; tr[tid][2] = x1; tr[tid][3] = y1;
        tr[tid][4] = (x1 - x0) * (y1 - y0);
    }
    __syncthreads();

    int p0 = blockIdx.x * 1024 + tid;  // chunk priors: p0 + 256*i
    float bx0[4], by0[4], bx1[4], by1[4], ar[4];
#pragma unroll
    for (int i = 0; i < 4; i++) {
        float4 pr = ((const float4*)priors)[p0 + 256 * i];
        float hw = pr.z * 0.5f, hh = pr.w * 0.5f;
        bx0[i] = pr.x - hw; by0[i] = pr.y - hh;
        bx1[i] = pr.x + hw; by1[i] = pr.y + hh;
        ar[i] = (bx1[i] - bx0[i]) * (by1[i] - by0[i]);
    }
    float bestI[4] = {-1.f, -1.f, -1.f, -1.f};
    int bestT[4] = {0, 0, 0, 0};
    unsigned long long best[NT_];
#pragma unroll
    for (int t = 0; t < NT_; t++) best[t] = 0ULL;

#pragma unroll
    for (int t = 0; t < NT_; t++) {
        float tx0 = tr[t][0], ty0 = tr[t][1], tx1 = tr[t][2], ty1 = tr[t][3], ta = tr[t][4];
        float mi = -1.0f; int pi = 0;
#pragma unroll
        for (int i = 0; i < 4; i++) {
            float iou = iou_fast(tx0, ty0, tx1, ty1, ta, bx0[i], by0[i], bx1[i], by1[i], ar[i]);
            if (iou > bestI[i]) { bestI[i] = iou; bestT[i] = t; }  // first-wins (t asc)
            if (iou > mi) { mi = iou; pi = i; }                    // first-wins (p asc)
        }
        unsigned long long pk = (((unsigned long long)__float_as_uint(mi)) << 32)
                              | (unsigned)(~(p0 + 256 * pi));
        if (pk > best[t]) best[t] = pk;
    }

    float ll_acc = 0.0f, pc_acc = 0.0f;
    int np_acc = 0;
#pragma unroll
    for (int i = 0; i < 4; i++) {
        int p = p0 + 256 * i;
        size_t bp = (size_t)b * NP_ + p;
        bool pos = !(bestI[i] < 0.5f);
        float2 c = ((const float2*)conf)[bp];
        float d = c.y - c.x;
        float v = pos ? 0.0f : softplus_(d);   // loss_c_mine value
        int bin = min(HB - 1, (int)(v * HSCALE));
        atomicAdd(&hc[bin], 1);
        atomicAdd(&hs[bin], v);
        if (pos) {
            np_acc++;
            pc_acc += softplus_(-d);  // lse - c.y
            int t = bestT[i];
            float tx0 = tr[t][0], ty0 = tr[t][1], tx1 = tr[t][2], ty1 = tr[t][3];
            float4 pr = ((const float4*)priors)[p];
            float gcx = ((tx0 + tx1) * 0.5f - pr.x) / (0.1f * pr.z);
            float gcy = ((ty0 + ty1) * 0.5f - pr.y) / (0.1f * pr.w);
            float gw = __logf((tx1 - tx0) / pr.z) * 5.0f;
            float gh = __logf((ty1 - ty0) / pr.w) * 5.0f;
            float4 ld = ((const float4*)loc)[bp];
            float d0 = fabsf(ld.x - gcx), d1 = fabsf(ld.y - gcy);
            float d2 = fabsf(ld.z - gw),  d3 = fabsf(ld.w - gh);
            ll_acc += (d0 < 1.0f) ? 0.5f * d0 * d0 : d0 - 0.5f;
            ll_acc += (d1 < 1.0f) ? 0.5f * d1 * d1 : d1 - 0.5f;
            ll_acc += (d2 < 1.0f) ? 0.5f * d2 * d2 : d2 - 0.5f;
            ll_acc += (d3 < 1.0f) ? 0.5f * d3 * d3 : d3 - 0.5f;
        }
    }

    int wave = tid >> 6, lane = tid & 63;
#pragma unroll
    for (int t = 0; t < NT_; t++) {
        unsigned long long v = best[t];
        for (int off = 32; off > 0; off >>= 1) {
            unsigned long long u = shfl_down_u64(v, off);
            if (u > v) v = u;
        }
        if (lane == 0) shb[wave][t] = v;
    }
    for (int off = 32; off > 0; off >>= 1) {
        ll_acc += __shfl_down(ll_acc, off, 64);
        pc_acc += __shfl_down(pc_acc, off, 64);
        np_acc += __shfl_down(np_acc, off, 64);
    }
    if (lane == 0) { sh_ll[wave] = ll_acc; sh_pc[wave] = pc_acc; sh_np[wave] = np_acc; }
    __syncthreads();  // also fences all LDS hist atomics

    if (tid < NT_) {
        unsigned long long v = shb[0][tid];
        for (int w = 1; w < 4; w++) { unsigned long long u = shb[w][tid]; if (u > v) v = u; }
        atomicMax(&bestPrior[b * NT_ + tid], v);
    }
    if (tid == 0) {
        float a = sh_ll[0] + sh_ll[1] + sh_ll[2] + sh_ll[3];
        float c2 = sh_pc[0] + sh_pc[1] + sh_pc[2] + sh_pc[3];
        int n = sh_np[0] + sh_np[1] + sh_np[2] + sh_np[3];
        if (a != 0.0f) atomicAdd(&sums_ll[b], a);
        if (c2 != 0.0f) atomicAdd(&sums_pc[b], c2);
        if (n) atomicAdd(&num_pos[b], n);
    }
    // zero-skip merge of the block-local histogram into the per-batch hist
    for (int i = tid; i < HB; i += 256) {
        int c = hc[i];
        if (c) {
            atomicAdd(&hcnt[b * HB + i], c);
            atomicAdd(&hsum[b * HB + i], hs[i]);
        }
    }
}

// Force-match correction: replace original contribution of each (b,t) best
// prior with the forced-pos contribution; remove its value from the hist.
__global__ void fixup(const float* __restrict__ loc, const float* __restrict__ conf,
                      const float* __restrict__ priors, const float* __restrict__ targets,
                      const unsigned long long* __restrict__ bestPrior,
                      int* __restrict__ num_pos, float* __restrict__ sums_ll,
                      float* __restrict__ sums_pc, int* __restrict__ hcnt,
                      float* __restrict__ hsum)
{
    int b = blockIdx.x;
    int t = threadIdx.x;  // 64 threads, 16 active
    __shared__ unsigned ps[NT_];
    __shared__ float tr[NT_][4];
    __shared__ float ta[NT_];
    if (t < NT_) {
        ps[t] = ~((unsigned)(bestPrior[b * NT_ + t] & 0xffffffffULL));
        const float* tp = targets + ((size_t)b * NT_ + t) * 5;
        tr[t][0] = tp[0]; tr[t][1] = tp[1]; tr[t][2] = tp[2]; tr[t][3] = tp[3];
        ta[t] = (tp[2] - tp[0]) * (tp[3] - tp[1]);
    }
    __syncthreads();
    if (t >= NT_) return;
    unsigned p = ps[t];
    for (int u = t + 1; u < NT_; u++)
        if (ps[u] == p) return;  // last-wins dedup

    float4 pr = ((const float4*)priors)[p];
    float hw = pr.z * 0.5f, hh = pr.w * 0.5f;
    float bx0 = pr.x - hw, by0 = pr.y - hh;
    float bx1 = pr.x + hw, by1 = pr.y + hh;
    float areab = (bx1 - bx0) * (by1 - by0);
    float bestI = -1.0f;
    int t0 = 0;
#pragma unroll
    for (int tt = 0; tt < NT_; tt++) {
        float iou = iou_fast(tr[tt][0], tr[tt][1], tr[tt][2], tr[tt][3], ta[tt],
                             bx0, by0, bx1, by1, areab);
        if (iou > bestI) { bestI = iou; t0 = tt; }
    }
    bool pos0 = !(bestI < 0.5f);  // bit-identical to fusedAC's decision

    size_t bp = (size_t)b * NP_ + p;
    float2 c = ((const float2*)conf)[bp];
    float d = c.y - c.x;
    float4 ld = ((const float4*)loc)[bp];

    auto sl1_of = [&](int tt) -> float {
        float tx0 = tr[tt][0], ty0 = tr[tt][1], tx1 = tr[tt][2], ty1 = tr[tt][3];
        float gcx = ((tx0 + tx1) * 0.5f - pr.x) / (0.1f * pr.z);
        float gcy = ((ty0 + ty1) * 0.5f - pr.y) / (0.1f * pr.w);
        float gw = __logf((tx1 - tx0) / pr.z) * 5.0f;
        float gh = __logf((ty1 - ty0) / pr.w) * 5.0f;
        float d0 = fabsf(ld.x - gcx), d1 = fabsf(ld.y - gcy);
        float d2 = fabsf(ld.z - gw),  d3 = fabsf(ld.w - gh);
        float s = (d0 < 1.0f) ? 0.5f * d0 * d0 : d0 - 0.5f;
        s += (d1 < 1.0f) ? 0.5f * d1 * d1 : d1 - 0.5f;
        s += (d2 < 1.0f) ? 0.5f * d2 * d2 : d2 - 0.5f;
        s += (d3 < 1.0f) ? 0.5f * d3 * d3 : d3 - 0.5f;
        return s;
    };

    float dll = sl1_of(t) - (pos0 ? sl1_of(t0) : 0.0f);
    if (dll != 0.0f) atomicAdd(&sums_ll[b], dll);
    if (!pos0) {
        float v = softplus_(d);  // original mine value, bit-identical to fusedAC
        int bin = min(HB - 1, (int)(v * HSCALE));
        atomicSub(&hcnt[b * HB + bin], 1);
        atomicAdd(&hsum[b * HB + bin], -v);
        atomicAdd(&sums_pc[b], softplus_(-d));
        atomicAdd(&num_pos[b], 1);
    }
}

// D2: per-batch top-K sum from the 1024-bin histogram; remainder uses the
// cut bin's mean value (error <= rem * binwidth, negligible vs threshold).
__global__ void __launch_bounds__(256) selectD2(const int* __restrict__ hcnt,
                                                const float* __restrict__ hsum,
                                                const int* __restrict__ num_pos,
                                                float* __restrict__ topk) {
    int b = blockIdx.x;
    __shared__ int cnt[HB];
    __shared__ float sm[HB];
    __shared__ unsigned ccnt[16];
    __shared__ float csm[16];
    int tid = threadIdx.x;
    for (int i = tid; i < HB; i += 256) {
        cnt[i] = hcnt[b * HB + i];
        sm[i] = hsum[b * HB + i];
    }
    __syncthreads();
    if (tid < 16) {
        unsigned c = 0; float s = 0.0f;
        for (int j = 0; j < 64; j++) { c += (unsigned)cnt[tid * 64 + j]; s += sm[tid * 64 + j]; }
        ccnt[tid] = c; csm[tid] = s;
    }
    __syncthreads();
    if (tid == 0) {
        int K = 3 * num_pos[b];
        if (K > NP_ - 1) K = NP_ - 1;
        float tk = 0.0f;
        if (K > 0) {
            unsigned need = (unsigned)K, cum = 0;
            float s = 0.0f;
            int cb = 15;
            for (; cb > 0; --cb) {
                if (cum + ccnt[cb] >= need) break;
                cum += ccnt[cb]; s += csm[cb];
            }
            int bin = cb * 64 + 63;
            for (; bin > cb * 64; --bin) {
                if (cum + (unsigned)cnt[bin] >= need) break;
                cum += (unsigned)cnt[bin]; s += sm[bin];
            }
            unsigned rem = need - cum;
            int c = cnt[bin];
            float avg = (c > 0) ? __fdividef(sm[bin], (float)c) : 0.0f;
            tk = s + (float)rem * avg;
        }
        topk[b] = tk;
    }
}

__global__ void finalD4(const int* __restrict__ num_pos, const float* __restrict__ sums_ll,
                        const float* __restrict__ sums_pc, const float* __restrict__ topk,
                        float* __restrict__ out) {
    int t = threadIdx.x;  // 64
    float ll = 0.0f, pc = 0.0f, tk = 0.0f;
    int n = 0;
    if (t < NB_) { ll = sums_ll[t]; pc = sums_pc[t]; tk = topk[t]; n = num_pos[t]; }
    for (int off = 32; off > 0; off >>= 1) {
        ll += __shfl_down(ll, off, 64);
        pc += __shfl_down(pc, off, 64);
        tk += __shfl_down(tk, off, 64);
        n  += __shfl_down(n, off, 64);
    }
    if (t == 0) {
        float fn = (float)n;
        out[0] = ll / fn;
        out[1] = (pc + tk) / fn;
    }
}

extern "C" void kernel_launch(void* const* d_in, const int* in_sizes, int n_in,
                              void* d_out, int out_size, void* d_ws, size_t ws_size,
                              hipStream_t stream) {
    const float* loc = (const float*)d_in[0];
    const float* conf = (const float*)d_in[1];
    const float* priors = (const float*)d_in[2];
    const float* targets = (const float*)d_in[3];
    float* out = (float*)d_out;

    char* w = (char*)d_ws;
    int* hcnt = (int*)w;                                        // 32*1024*4 = 128 KB
    float* hsum = (float*)(w + (128u << 10));                   // 128 KB
    char* acc = w + (256u << 10);
    unsigned long long* bestPrior = (unsigned long long*)acc;   // 4 KB
    int* num_pos = (int*)(acc + 4096);                          // 128 B
    float* sums_ll = (float*)(acc + 4224);
    float* sums_pc = (float*)(acc + 4352);
    float* topk    = (float*)(acc + 4480);

    hipMemsetAsync(w, 0, (256u << 10) + 8192, stream);
    fusedAC<<<dim3(64, 32), 256, 0, stream>>>(loc, conf, priors, targets, bestPrior,
                                              num_pos, sums_ll, sums_pc, hcnt, hsum);
    fixup<<<NB_, 64, 0, stream>>>(loc, conf, priors, targets, bestPrior,
                                  num_pos, sums_ll, sums_pc, hcnt, hsum);
    selectD2<<<NB_, 256, 0, stream>>>(hcnt, hsum, num_pos, topk);
    finalD4<<<1, 64, 0, stream>>>(num_pos, sums_ll, sums_pc, topk, out);
}